// Round 14
// baseline (14231.227 us; speedup 1.0000x reference)
//
#include <hip/hip_runtime.h>
#include <hip/hip_bf16.h>
#include <stdint.h>

// LSTM (T=1024, B=64, D=512, H=512) on gfx950.
// R14: fused GEMM-fill + clock-measurement round.
//  - 256 WGs: 64 team WGs (8 teams x 8 slots, XCD election, R4 flag protocol)
//    + 192 workers. X-GEMM is decomposed into 64x128 tiles pulled from a
//    private per-WG cursor; team WGs grind tiles (or register-only junk-MFMA
//    heater quanta) BETWEEN flag polls, so the wait time is filled with work
//    on the team CU itself. Workers grind their tiles then heat until done.
//  - WG 256 = clock probe: samples clock64()/wall_clock64() at ~400us into
//    the run, stores ratio to ctl[20]. k_probe (separate kernel) busy-waits
//    5000us + ratio*100us so the measured core clock is READABLE as a
//    rocprof dispatch duration. ~5.7ms => ~700MHz (downclock world),
//    >=7ms => >=2GHz (real-latency world).

typedef float    f32x4  __attribute__((ext_vector_type(4)));
typedef short    s16x8  __attribute__((ext_vector_type(8)));
typedef unsigned short u16;
typedef u16      u16x4  __attribute__((ext_vector_type(4)));
typedef unsigned int u32;
typedef unsigned long long u64;

#define TT 1024
#define BB 64
#define DD 512
#define HH 512
#define NG 2048
#define NTEAM 8
#define NSLOT 8
#define NLW 256        // working WGs; +1 probe WG
#define CHUNK_STEPS 32
#define NCHUNK 32
#define TPC 512        // tiles per chunk: 32 row-tiles(64) x 16 col-tiles(128)
#define NTILES 16384

__device__ __forceinline__ u16 f2bf(float f) {
  __hip_bfloat16 h = __float2bfloat16(f);
  union { __hip_bfloat16 b; u16 u; } v; v.b = h; return v.u;
}
__device__ __forceinline__ float bf2f(u16 u) {
  union { unsigned int i; float f; } v; v.i = ((unsigned int)u) << 16; return v.f;
}
__device__ __forceinline__ float sig_fast(float x) { return 1.f / (1.f + __expf(-x)); }
__device__ __forceinline__ float tanh_fast(float x) { return 1.f - 2.f / (1.f + __expf(2.f * x)); }

__device__ __forceinline__ void gload_lds16(const u16* g, u16* l) {
  __builtin_amdgcn_global_load_lds(
      (const __attribute__((address_space(1))) unsigned int*)g,
      (__attribute__((address_space(3))) unsigned int*)l, 16, 0, 0);
}
__device__ __forceinline__ void st_plain(u32* p, u32 v) {
  asm volatile("global_store_dword %0, %1, off" :: "v"(p), "v"(v) : "memory");
}
__device__ __forceinline__ void st_short_sc1(u16* p, u16 v) {
  asm volatile("global_store_short %0, %1, off sc1" :: "v"(p), "v"((u32)v) : "memory");
}

// ---------------- setup kernels ----------------
__global__ void k_cast(const float* __restrict__ in, u16* __restrict__ out, long n) {
  long i = ((long)blockIdx.x * blockDim.x + threadIdx.x) * 4;
  if (i >= n) return;
  const float4 v = *(const float4*)(in + i);
  u16x4 o; o.x = f2bf(v.x); o.y = f2bf(v.y); o.z = f2bf(v.z); o.w = f2bf(v.w);
  *(u16x4*)(out + i) = o;
}

__global__ void k_pack(const float* __restrict__ Wxi, const float* __restrict__ Whi, const float* __restrict__ bi,
                       const float* __restrict__ Wxf, const float* __restrict__ Whf, const float* __restrict__ bfi,
                       const float* __restrict__ Wxo, const float* __restrict__ Who, const float* __restrict__ bo,
                       const float* __restrict__ Wxc, const float* __restrict__ Whc, const float* __restrict__ bc,
                       u16* __restrict__ WxT, u16* __restrict__ WhT, float* __restrict__ biasp)
{
  const int k = blockIdx.x;
  const float* Wx[4] = {Wxi, Wxf, Wxo, Wxc};
  const float* Wh[4] = {Whi, Whf, Who, Whc};
  for (int h = threadIdx.x; h < HH; h += blockDim.x) {
#pragma unroll
    for (int g = 0; g < 4; ++g) {
      const long n = h * 4 + g;
      WxT[n * DD + k] = f2bf(Wx[g][(long)k * HH + h]);
      WhT[n * HH + k] = f2bf(Wh[g][(long)k * HH + h]);
    }
  }
  if (k == 0) {
    const float* bp[4] = {bi, bfi, bo, bc};
    for (int n = threadIdx.x; n < NG; n += blockDim.x)
      biasp[n] = bp[n & 3][n >> 2];
  }
}

// ---------------- fused kernel ----------------
__global__ __launch_bounds__(512, 2) void k_fused(
    const u16* __restrict__ inbf, const u16* __restrict__ WxT,
    const u16* __restrict__ WhT, const float* __restrict__ biasp,
    u16* __restrict__ X, u16* __restrict__ Hh,
    float* __restrict__ dout, float* __restrict__ doutH, float* __restrict__ doutC,
    u32* __restrict__ ctl, u32* __restrict__ flags, u32* __restrict__ cnt)
{
  __shared__ __align__(16) u16 As[64 * 64];
  __shared__ __align__(16) u16 Bs[128 * 64];
  __shared__ __align__(16) float pre[8][260];
  __shared__ int s_team, s_slot, s_mixed, s_go;
  const int tid = threadIdx.x;
  const int wgid = blockIdx.x;
  const int l = tid & 63, wv = tid >> 6;
  const int lr = l >> 3, lc = l & 7;
  const int cl = l & 15, rg = l >> 4;

  // ---------- clock probe WG ----------
  if (wgid == NLW) {
    if (tid == 0) {
      u64 r0 = wall_clock64();
      while (wall_clock64() - r0 < 40000ULL) __builtin_amdgcn_s_sleep(32);  // ~400us
      u64 c0 = clock64(); r0 = wall_clock64();
      while (wall_clock64() - r0 < 10000ULL) {}                             // 100us window
      u64 c1 = clock64(); u64 r1 = wall_clock64();
      u32 ratio = (u32)((c1 - c0) / (r1 - r0));   // core cyc per 100MHz tick
      __hip_atomic_store(&ctl[20], ratio, __ATOMIC_RELAXED, __HIP_MEMORY_SCOPE_AGENT);
    }
    return;
  }

  // heater state
  const s16x8 jin = (s16x8){0x3f80,0x3f80,0x3f80,0x3f80,0x3f80,0x3f80,0x3f80,0x3f80};
  f32x4 j0 = (f32x4){0.f,0.f,0.f,0.f}, j1 = j0, j2 = j0, j3 = j0;
  int mytau = wgid;

  auto heater = [&]() {
#pragma unroll
    for (int i = 0; i < 32; ++i) {
      j0 = __builtin_amdgcn_mfma_f32_16x16x32_bf16(jin, jin, j0, 0, 0, 0);
      j1 = __builtin_amdgcn_mfma_f32_16x16x32_bf16(jin, jin, j1, 0, 0, 0);
      j2 = __builtin_amdgcn_mfma_f32_16x16x32_bf16(jin, jin, j2, 0, 0, 0);
      j3 = __builtin_amdgcn_mfma_f32_16x16x32_bf16(jin, jin, j3, 0, 0, 0);
    }
  };

  auto do_tile = [&](int tau) {
    const int c = tau / TPC;
    const int u = tau - c * TPC;
    const int r = u >> 4;
    const int q = u & 15;
    const long arow0 = (long)c * 2048 + r * 64;
    const int  bcol  = q * 128;
    f32x4 tac[4];
#pragma unroll
    for (int m = 0; m < 4; ++m) tac[m] = (f32x4){0.f,0.f,0.f,0.f};
    for (int k0 = 0; k0 < DD; k0 += 64) {
      gload_lds16(inbf + (arow0 + wv * 8 + lr) * DD + k0 + lc * 8,
                  &As[(wv * 8 + lr) * 64 + lc * 8]);
#pragma unroll
      for (int j = 0; j < 2; ++j) {
        const int sub = wv * 2 + j;
        gload_lds16(WxT + (long)(bcol + sub * 8 + lr) * DD + k0 + lc * 8,
                    &Bs[(sub * 8 + lr) * 64 + lc * 8]);
      }
      __syncthreads();
#pragma unroll
      for (int kk = 0; kk < 2; ++kk) {
        s16x8 bfx = *(const s16x8*)&Bs[(wv * 16 + cl) * 64 + kk * 32 + rg * 8];
#pragma unroll
        for (int m = 0; m < 4; ++m) {
          s16x8 afx = *(const s16x8*)&As[(m * 16 + cl) * 64 + kk * 32 + rg * 8];
          tac[m] = __builtin_amdgcn_mfma_f32_16x16x32_bf16(afx, bfx, tac[m], 0, 0, 0);
        }
      }
      __syncthreads();
    }
    const int col = bcol + wv * 16 + cl;
    const float bv = biasp[col];
#pragma unroll
    for (int m = 0; m < 4; ++m)
#pragma unroll
      for (int j = 0; j < 4; ++j)
        st_short_sc1(&X[(arow0 + m * 16 + rg * 4 + j) * NG + col], f2bf(tac[m][j] + bv));
    asm volatile("s_waitcnt vmcnt(0)" ::: "memory");
    __syncthreads();
    if (tid == 0)
      __hip_atomic_fetch_add(&cnt[c * 32], 1u, __ATOMIC_RELAXED, __HIP_MEMORY_SCOPE_AGENT);
  };

  auto quantum = [&]() {
    if (mytau < NTILES) { do_tile(mytau); mytau += NLW; }
    else heater();
  };

  // ---------- election ----------
  if (tid == 0) {
    u32 x;
    asm volatile("s_getreg_b32 %0, hwreg(HW_REG_XCC_ID)" : "=s"(x));
    x &= 7u;
    u32 r = __hip_atomic_fetch_add(&ctl[x], 1u, __ATOMIC_RELAXED, __HIP_MEMORY_SCOPE_AGENT);
    u32 p = 0;
    if (r >= NSLOT)
      p = __hip_atomic_fetch_add(&ctl[8], 1u, __ATOMIC_RELAXED, __HIP_MEMORY_SCOPE_AGENT);
    __hip_atomic_fetch_add(&ctl[9], 1u, __ATOMIC_RELAXED, __HIP_MEMORY_SCOPE_AGENT);
    while (__hip_atomic_load(&ctl[9], __ATOMIC_RELAXED, __HIP_MEMORY_SCOPE_AGENT) < (u32)NLW)
      __builtin_amdgcn_s_sleep(4);
    u32 c[8];
#pragma unroll
    for (int i = 0; i < 8; ++i)
      c[i] = __hip_atomic_load(&ctl[i], __ATOMIC_RELAXED, __HIP_MEMORY_SCOPE_AGENT);
    int team = -1, slot = 0;
    if (r < NSLOT) { team = (int)x; slot = (int)r; }
    else {
      u32 acc = 0;
      for (int tt = 0; tt < 8; ++tt) {
        u32 have = c[tt] < NSLOT ? c[tt] : NSLOT;
        u32 miss = NSLOT - have;
        if (team < 0 && p < acc + miss) { team = tt; slot = (int)(have + (p - acc)); }
        acc += miss;
      }
    }
    s_team = team; s_slot = slot;
    s_mixed = (team >= 0 && c[team] < NSLOT) ? 1 : 0;
  }
  __syncthreads();
  const int team = s_team, slot = s_slot, mixed = s_mixed;

  if (team < 0) {
    // ---------- worker: grind all own tiles, then heat until teams done ----------
    while (mytau < NTILES) { do_tile(mytau); mytau += NLW; __syncthreads(); }
    for (;;) {
      if (tid == 0)
        s_go = (__hip_atomic_load(&ctl[16], __ATOMIC_RELAXED, __HIP_MEMORY_SCOPE_AGENT) >= 64u);
      __syncthreads();
      if (s_go) break;
#pragma unroll 1
      for (int h = 0; h < 16; ++h) heater();
      __syncthreads();
    }
    asm volatile("" :: "v"(j0), "v"(j1), "v"(j2), "v"(j3));
    return;
  }

  // ---------- team path ----------
  const int gcol0 = slot * 256 + wv * 32;
  s16x8 bfr[2][16];
#pragma unroll
  for (int nt = 0; nt < 2; ++nt)
#pragma unroll
    for (int ks = 0; ks < 16; ++ks)
      bfr[nt][ks] = *(const s16x8*)&WhT[(long)(gcol0 + nt * 16 + cl) * HH + ks * 32 + rg * 8];

  const int prow = wv;
  const int phl  = tid & 63;
  const int grow = team * 8 + prow;
  const int ghl  = slot * 64 + phl;
  float creg = 0.f;
  u32* myflag = &flags[(team * 8 + slot) * 32];

  for (int t = 0; t < TT; ++t) {
    if ((t & (CHUNK_STEPS - 1)) == 0) {           // X chunk gate (self-helping)
      const int c = t >> 5;
      for (;;) {
        if (tid == 0)
          s_go = (__hip_atomic_load(&cnt[c * 32], __ATOMIC_RELAXED, __HIP_MEMORY_SCOPE_AGENT) >= (u32)TPC);
        __syncthreads();
        if (s_go) break;
        quantum();
        __syncthreads();
      }
    }
    u16x4 xv = *(const u16x4*)&X[((long)t * BB + grow) * NG + slot * 256 + phl * 4];

    if (t > 0) {                                  // H-flag wait, filled with quanta
      for (;;) {
        if (wv == 0) {
          u32 v = (l < NSLOT)
            ? __hip_atomic_load(&flags[(team * 8 + l) * 32], __ATOMIC_RELAXED, __HIP_MEMORY_SCOPE_AGENT)
            : (u32)t;
          unsigned long long b = __ballot(v >= (u32)t);
          if (l == 0) s_go = (b == ~0ULL) ? 1 : 0;
        }
        __syncthreads();
        if (s_go) break;
        quantum();
        __syncthreads();
      }
    }

    f32x4 a0a = (f32x4){0.f,0.f,0.f,0.f}, a0b = (f32x4){0.f,0.f,0.f,0.f};
    f32x4 a1a = (f32x4){0.f,0.f,0.f,0.f}, a1b = (f32x4){0.f,0.f,0.f,0.f};
    if (t > 0) {
      const u16* Hp = Hh + (long)(t - 1) * BB * HH;
      s16x8 af[16];
#pragma unroll
      for (int ks = 0; ks < 16; ++ks) af[ks] = (s16x8){0,0,0,0,0,0,0,0};
      if (cl < 8) {
#pragma unroll
        for (int ks = 0; ks < 16; ++ks)
          af[ks] = *(const s16x8*)&Hp[(team * 8 + cl) * HH + ks * 32 + rg * 8];
      }
#pragma unroll
      for (int ks = 0; ks < 16; ks += 2) {
        a0a = __builtin_amdgcn_mfma_f32_16x16x32_bf16(af[ks],     bfr[0][ks],     a0a, 0, 0, 0);
        a1a = __builtin_amdgcn_mfma_f32_16x16x32_bf16(af[ks],     bfr[1][ks],     a1a, 0, 0, 0);
        a0b = __builtin_amdgcn_mfma_f32_16x16x32_bf16(af[ks + 1], bfr[0][ks + 1], a0b, 0, 0, 0);
        a1b = __builtin_amdgcn_mfma_f32_16x16x32_bf16(af[ks + 1], bfr[1][ks + 1], a1b, 0, 0, 0);
      }
    }
    const f32x4 acc0 = a0a + a0b, acc1 = a1a + a1b;
    if (rg < 2) {
#pragma unroll
      for (int j = 0; j < 4; ++j) {
        pre[rg * 4 + j][wv * 32 + cl]      = acc0[j];
        pre[rg * 4 + j][wv * 32 + 16 + cl] = acc1[j];
      }
    }
    __syncthreads();

    f32x4 pv = *(const f32x4*)&pre[prow][phl * 4];
    const float pi = pv[0] + bf2f((u16)xv.x);
    const float pf = pv[1] + bf2f((u16)xv.y);
    const float po = pv[2] + bf2f((u16)xv.z);
    const float pc = pv[3] + bf2f((u16)xv.w);
    const float ig = sig_fast(pi);
    const float fg = sig_fast(pf);
    const float og = sig_fast(po);
    const float ct = tanh_fast(pc);
    creg = fg * creg + ig * ct;
    const float hv = og * tanh_fast(creg);
    const u16 hb = f2bf(hv);
    u16* hdst = &Hh[((long)t * BB + grow) * HH + ghl];
    if (!mixed) *hdst = hb;
    else asm volatile("global_store_short %0, %1, off sc1"
                      :: "v"(hdst), "v"((u32)hb) : "memory");

    dout[((long)t * BB + grow) * HH + ghl] = hv;
    if (t == TT - 1) {
      doutH[grow * HH + ghl] = hv;
      doutC[grow * HH + ghl] = creg;
    }
    asm volatile("s_waitcnt vmcnt(0)" ::: "memory");
    __syncthreads();
    if (tid == 0) {
      if (!mixed) st_plain(myflag, (u32)(t + 1));
      else __hip_atomic_store(myflag, (u32)(t + 1), __ATOMIC_RELAXED, __HIP_MEMORY_SCOPE_AGENT);
    }
  }

  __syncthreads();
  if (tid == 0)
    __hip_atomic_fetch_add(&ctl[16], 1u, __ATOMIC_RELAXED, __HIP_MEMORY_SCOPE_AGENT);
  asm volatile("" :: "v"(j0), "v"(j1), "v"(j2), "v"(j3));
}

// ---------------- clock report kernel: dur encodes measured core clock ----------------
__global__ void k_probe(const u32* __restrict__ ctl) {
  if (threadIdx.x == 0 && blockIdx.x == 0) {
    u32 r = ctl[20];
    if (r < 1u) r = 1u;
    if (r > 40u) r = 40u;
    // dur = 5000us + ratio*100us  (ratio = core MHz / 100)
    const u64 target = 500000ULL + (u64)r * 10000ULL;   // in 100MHz wall ticks
    u64 t0 = wall_clock64();
    while (wall_clock64() - t0 < target) __builtin_amdgcn_s_sleep(32);
  }
}

// ---------------- host ----------------
extern "C" void kernel_launch(void* const* d_in, const int* in_sizes, int n_in,
                              void* d_out, int out_size, void* d_ws, size_t ws_size,
                              hipStream_t stream)
{
  const float* inputs = (const float*)d_in[0];
  const float* W_xi = (const float*)d_in[1];
  const float* W_hi = (const float*)d_in[2];
  const float* b_i  = (const float*)d_in[3];
  const float* W_xf = (const float*)d_in[4];
  const float* W_hf = (const float*)d_in[5];
  const float* b_f  = (const float*)d_in[6];
  const float* W_xo = (const float*)d_in[7];
  const float* W_ho = (const float*)d_in[8];
  const float* b_o  = (const float*)d_in[9];
  const float* W_xc = (const float*)d_in[10];
  const float* W_hc = (const float*)d_in[11];
  const float* b_c  = (const float*)d_in[12];
  float* out = (float*)d_out;
  char* ws = (char*)d_ws;

  size_t off = 0;
  auto walloc = [&](size_t sz) { size_t o = off; off = (off + sz + 255) & ~(size_t)255; return o; };
  const size_t o_inbf  = walloc((size_t)TT * BB * DD * 2);   // 64 MB
  const size_t o_WxT   = walloc((size_t)NG * DD * 2);
  const size_t o_WhT   = walloc((size_t)NG * HH * 2);
  const size_t o_bias  = walloc((size_t)NG * 4);
  const size_t o_Hh    = walloc((size_t)TT * BB * HH * 2);   // 64 MB
  const size_t o_ctl   = walloc(256);
  const size_t o_flags = walloc(8192);
  const size_t o_cnt   = walloc((size_t)NCHUNK * 32 * 4);
  const size_t o_X     = walloc((size_t)TT * BB * NG * 2);   // 256 MB

  u16*   inbf  = (u16*)(ws + o_inbf);
  u16*   WxT   = (u16*)(ws + o_WxT);
  u16*   WhT   = (u16*)(ws + o_WhT);
  float* biasp = (float*)(ws + o_bias);
  u16*   Xbuf  = (u16*)(ws + o_X);
  u16*   Hh    = (u16*)(ws + o_Hh);

  k_cast<<<dim3((TT * BB * DD) / 1024), dim3(256), 0, stream>>>(inputs, inbf, (long)TT * BB * DD);
  k_pack<<<dim3(DD), dim3(256), 0, stream>>>(W_xi, W_hi, b_i, W_xf, W_hf, b_f,
                                             W_xo, W_ho, b_o, W_xc, W_hc, b_c,
                                             WxT, WhT, biasp);

  float* doutH = out + (size_t)TT * BB * HH;
  float* doutC = doutH + (size_t)BB * HH;

  hipMemsetAsync(ws + o_ctl, 0, 256, stream);
  hipMemsetAsync(ws + o_flags, 0, 8192, stream);
  hipMemsetAsync(ws + o_cnt, 0, (size_t)NCHUNK * 32 * 4, stream);

  k_fused<<<dim3(NLW + 1), dim3(512), 0, stream>>>(
      inbf, WxT, WhT, biasp, Xbuf, Hh, out, doutH, doutC,
      (u32*)(ws + o_ctl), (u32*)(ws + o_flags), (u32*)(ws + o_cnt));

  k_probe<<<dim3(1), dim3(64), 0, stream>>>((const u32*)(ws + o_ctl));
}

// Round 16
// 4290.003 us; speedup vs baseline: 3.3173x; 3.3173x over previous
//
#include <hip/hip_runtime.h>
#include <hip/hip_bf16.h>
#include <stdint.h>

// LSTM (T=1024, B=64, D=512, H=512) on gfx950.
// R16: THE SPILL FIX. k_lstm needs ~240 VGPRs/thread (bfr[2][16]=128 for
// weights + af[16]=64 + acc). __launch_bounds__(512,2) capped the allocator
// at 128 VGPRs -> the W_h register file spilled to scratch and was reloaded
// (256KB/WG) EVERY step: the ~6000-cycle invariant that survived ten sync
// variants (R4-R13). Fix: __launch_bounds__(512,1) -> 256 VGPR budget.
// Only 64 WGs on 256 CUs, so 1 WG/CU occupancy costs nothing.
// Protocol: R4 (election, tight agent poll, plain H-history exchange).

typedef float    f32x4  __attribute__((ext_vector_type(4)));
typedef short    s16x8  __attribute__((ext_vector_type(8)));
typedef unsigned short u16;
typedef u16      u16x4  __attribute__((ext_vector_type(4)));
typedef unsigned int u32;

#define TT 1024
#define BB 64
#define DD 512
#define HH 512
#define NG 2048
#define NTEAM 8
#define NSLOT 8
#define NLW 128

__device__ __forceinline__ u16 f2bf(float f) {
  __hip_bfloat16 h = __float2bfloat16(f);
  union { __hip_bfloat16 b; u16 u; } v; v.b = h; return v.u;
}
__device__ __forceinline__ float bf2f(u16 u) {
  union { unsigned int i; float f; } v; v.i = ((unsigned int)u) << 16; return v.f;
}
__device__ __forceinline__ float sig_fast(float x) { return 1.f / (1.f + __expf(-x)); }
__device__ __forceinline__ float tanh_fast(float x) { return 1.f - 2.f / (1.f + __expf(2.f * x)); }

__device__ __forceinline__ void gload_lds16(const u16* g, u16* l) {
  __builtin_amdgcn_global_load_lds(
      (const __attribute__((address_space(1))) unsigned int*)g,
      (__attribute__((address_space(3))) unsigned int*)l, 16, 0, 0);
}
__device__ __forceinline__ void st_plain(u32* p, u32 v) {
  asm volatile("global_store_dword %0, %1, off" :: "v"(p), "v"(v) : "memory");
}

// ---------------- setup ----------------
__global__ void k_cast(const float* __restrict__ in, u16* __restrict__ out, long n) {
  long i = ((long)blockIdx.x * blockDim.x + threadIdx.x) * 4;
  if (i >= n) return;
  const float4 v = *(const float4*)(in + i);
  u16x4 o; o.x = f2bf(v.x); o.y = f2bf(v.y); o.z = f2bf(v.z); o.w = f2bf(v.w);
  *(u16x4*)(out + i) = o;
}

__global__ void k_pack(const float* __restrict__ Wxi, const float* __restrict__ Whi, const float* __restrict__ bi,
                       const float* __restrict__ Wxf, const float* __restrict__ Whf, const float* __restrict__ bfi,
                       const float* __restrict__ Wxo, const float* __restrict__ Who, const float* __restrict__ bo,
                       const float* __restrict__ Wxc, const float* __restrict__ Whc, const float* __restrict__ bc,
                       u16* __restrict__ WxT, u16* __restrict__ WhT, float* __restrict__ biasp)
{
  const int k = blockIdx.x;
  const float* Wx[4] = {Wxi, Wxf, Wxo, Wxc};
  const float* Wh[4] = {Whi, Whf, Who, Whc};
  for (int h = threadIdx.x; h < HH; h += blockDim.x) {
#pragma unroll
    for (int g = 0; g < 4; ++g) {
      const long n = h * 4 + g;
      WxT[n * DD + k] = f2bf(Wx[g][(long)k * HH + h]);
      WhT[n * HH + k] = f2bf(Wh[g][(long)k * HH + h]);
    }
  }
  if (k == 0) {
    const float* bp[4] = {bi, bfi, bo, bc};
    for (int n = threadIdx.x; n < NG; n += blockDim.x)
      biasp[n] = bp[n & 3][n >> 2];
  }
}

// ---------------- phase 1: X GEMM ----------------
__global__ __launch_bounds__(256) void k_gemm_x(
    const u16* __restrict__ A, const u16* __restrict__ BT,
    const float* __restrict__ biasp, u16* __restrict__ X)
{
  __shared__ __align__(16) u16 As[128 * 64];
  __shared__ __align__(16) u16 Bs[128 * 64];
  const int tid = threadIdx.x;
  const int l = tid & 63;
  const int w = tid >> 6;
  const int wr = w >> 1, wc = w & 1;
  const long brow = (long)blockIdx.y * 128;
  const int  bcol = blockIdx.x * 128;
  const int  lr = l >> 3, lc = l & 7;
  const int  cl = l & 15, rg = l >> 4;

  f32x4 acc[4][4];
#pragma unroll
  for (int m = 0; m < 4; ++m)
#pragma unroll
    for (int n = 0; n < 4; ++n) acc[m][n] = (f32x4){0.f, 0.f, 0.f, 0.f};

  for (int k0 = 0; k0 < DD; k0 += 64) {
#pragma unroll
    for (int j = 0; j < 4; ++j) {
      const int sub = w * 4 + j;
      gload_lds16(A  + (brow + sub * 8 + lr) * DD + k0 + lc * 8, &As[sub * 512]);
      gload_lds16(BT + ((long)(bcol + sub * 8 + lr)) * DD + k0 + lc * 8, &Bs[sub * 512]);
    }
    __syncthreads();
#pragma unroll
    for (int kk = 0; kk < 2; ++kk) {
      s16x8 af[4], bfr[4];
#pragma unroll
      for (int m = 0; m < 4; ++m)
        af[m] = *(const s16x8*)&As[(wr * 64 + m * 16 + cl) * 64 + kk * 32 + rg * 8];
#pragma unroll
      for (int n = 0; n < 4; ++n)
        bfr[n] = *(const s16x8*)&Bs[(wc * 64 + n * 16 + cl) * 64 + kk * 32 + rg * 8];
#pragma unroll
      for (int m = 0; m < 4; ++m)
#pragma unroll
        for (int n = 0; n < 4; ++n)
          acc[m][n] = __builtin_amdgcn_mfma_f32_16x16x32_bf16(af[m], bfr[n], acc[m][n], 0, 0, 0);
    }
    __syncthreads();
  }
#pragma unroll
  for (int n = 0; n < 4; ++n) {
    const int col = bcol + wc * 64 + n * 16 + cl;
    const float bv = biasp[col];
#pragma unroll
    for (int m = 0; m < 4; ++m)
#pragma unroll
      for (int j = 0; j < 4; ++j) {
        const long row = brow + wr * 64 + m * 16 + rg * 4 + j;
        X[row * NG + col] = f2bf(acc[m][n][j] + bv);
      }
  }
}

// ---------------- phase 2: recurrent kernel (R4 protocol, 256-VGPR budget) ----------------
__global__ __launch_bounds__(512, 1) void k_lstm(
    const u16* __restrict__ X, const u16* __restrict__ WhT,
    u16* __restrict__ Hh,
    float* __restrict__ dout, float* __restrict__ doutH, float* __restrict__ doutC,
    u32* __restrict__ ctl, u32* __restrict__ flags)
{
  __shared__ __align__(16) float pre[8][260];
  __shared__ int s_team, s_slot, s_mixed;
  const int tid = threadIdx.x;

  // ---- adaptive team formation (placement-robust, deadlock-free) ----
  if (tid == 0) {
    u32 x;
    asm volatile("s_getreg_b32 %0, hwreg(HW_REG_XCC_ID)" : "=s"(x));
    x &= 7u;
    u32 r = __hip_atomic_fetch_add(&ctl[x], 1u, __ATOMIC_RELAXED, __HIP_MEMORY_SCOPE_AGENT);
    u32 p = 0;
    if (r >= NSLOT)
      p = __hip_atomic_fetch_add(&ctl[8], 1u, __ATOMIC_RELAXED, __HIP_MEMORY_SCOPE_AGENT);
    __hip_atomic_fetch_add(&ctl[9], 1u, __ATOMIC_RELAXED, __HIP_MEMORY_SCOPE_AGENT);
    while (__hip_atomic_load(&ctl[9], __ATOMIC_RELAXED, __HIP_MEMORY_SCOPE_AGENT) < (u32)NLW)
      __builtin_amdgcn_s_sleep(4);
    u32 c[8];
#pragma unroll
    for (int i = 0; i < 8; ++i)
      c[i] = __hip_atomic_load(&ctl[i], __ATOMIC_RELAXED, __HIP_MEMORY_SCOPE_AGENT);
    int team = -1, slot = 0;
    if (r < NSLOT) { team = (int)x; slot = (int)r; }
    else {
      u32 acc = 0;
      for (int tt = 0; tt < 8; ++tt) {
        u32 have = c[tt] < NSLOT ? c[tt] : NSLOT;
        u32 miss = NSLOT - have;
        if (team < 0 && p < acc + miss) { team = tt; slot = (int)(have + (p - acc)); }
        acc += miss;
      }
    }
    s_team = team; s_slot = slot;
    s_mixed = (team >= 0 && c[team] < NSLOT) ? 1 : 0;
  }
  __syncthreads();
  const int team = s_team, slot = s_slot, mixed = s_mixed;
  if (team < 0) return;

  const int l = tid & 63, wv = tid >> 6;
  const int cl = l & 15, rg = l >> 4;
  const int gcol0 = slot * 256 + wv * 32;

  // constant W_h fragments: 128 VGPRs/thread — MUST stay in registers
  s16x8 bfr[2][16];
#pragma unroll
  for (int nt = 0; nt < 2; ++nt)
#pragma unroll
    for (int ks = 0; ks < 16; ++ks)
      bfr[nt][ks] = *(const s16x8*)&WhT[(long)(gcol0 + nt * 16 + cl) * HH + ks * 32 + rg * 8];

  const int prow = tid >> 6;
  const int phl  = tid & 63;
  const int grow = team * 8 + prow;
  const int ghl  = slot * 64 + phl;
  float creg = 0.f;
  u32* myflag = &flags[(team * 8 + slot) * 32];

  for (int t = 0; t < TT; ++t) {
    u16x4 xv = *(const u16x4*)&X[((long)t * BB + grow) * NG + slot * 256 + phl * 4];

    if (t > 0) {
      if (wv == 0) {
        const u32 tgt = (u32)t;
        u32 vv; unsigned long long b;
        do {
          vv = (l < NSLOT)
             ? __hip_atomic_load(&flags[(team * 8 + l) * 32], __ATOMIC_RELAXED, __HIP_MEMORY_SCOPE_AGENT)
             : tgt;
          b = __ballot(vv >= tgt);
        } while (b != ~0ULL);
      }
      __syncthreads();
    }

    f32x4 a0a = (f32x4){0.f,0.f,0.f,0.f}, a0b = (f32x4){0.f,0.f,0.f,0.f};
    f32x4 a1a = (f32x4){0.f,0.f,0.f,0.f}, a1b = (f32x4){0.f,0.f,0.f,0.f};
    if (t > 0) {
      const u16* Hp = Hh + (long)(t - 1) * BB * HH;
      s16x8 af[16];
#pragma unroll
      for (int ks = 0; ks < 16; ++ks) af[ks] = (s16x8){0,0,0,0,0,0,0,0};
      if (cl < 8) {
#pragma unroll
        for (int ks = 0; ks < 16; ++ks)
          af[ks] = *(const s16x8*)&Hp[(team * 8 + cl) * HH + ks * 32 + rg * 8];
      }
#pragma unroll
      for (int ks = 0; ks < 16; ks += 2) {
        a0a = __builtin_amdgcn_mfma_f32_16x16x32_bf16(af[ks],     bfr[0][ks],     a0a, 0, 0, 0);
        a1a = __builtin_amdgcn_mfma_f32_16x16x32_bf16(af[ks],     bfr[1][ks],     a1a, 0, 0, 0);
        a0b = __builtin_amdgcn_mfma_f32_16x16x32_bf16(af[ks + 1], bfr[0][ks + 1], a0b, 0, 0, 0);
        a1b = __builtin_amdgcn_mfma_f32_16x16x32_bf16(af[ks + 1], bfr[1][ks + 1], a1b, 0, 0, 0);
      }
    }
    const f32x4 acc0 = a0a + a0b, acc1 = a1a + a1b;
    if (rg < 2) {
#pragma unroll
      for (int j = 0; j < 4; ++j) {
        pre[rg * 4 + j][wv * 32 + cl]      = acc0[j];
        pre[rg * 4 + j][wv * 32 + 16 + cl] = acc1[j];
      }
    }
    __syncthreads();

    f32x4 pv = *(const f32x4*)&pre[prow][phl * 4];
    const float pi = pv[0] + bf2f((u16)xv.x);
    const float pf = pv[1] + bf2f((u16)xv.y);
    const float po = pv[2] + bf2f((u16)xv.z);
    const float pc = pv[3] + bf2f((u16)xv.w);
    const float ig = sig_fast(pi);
    const float fg = sig_fast(pf);
    const float og = sig_fast(po);
    const float ct = tanh_fast(pc);
    creg = fg * creg + ig * ct;
    const float hv = og * tanh_fast(creg);
    const u16 hb = f2bf(hv);
    u16* hdst = &Hh[((long)t * BB + grow) * HH + ghl];
    if (!mixed) *hdst = hb;
    else asm volatile("global_store_short %0, %1, off sc1"
                      :: "v"(hdst), "v"((u32)hb) : "memory");

    dout[((long)t * BB + grow) * HH + ghl] = hv;
    if (t == TT - 1) {
      doutH[grow * HH + ghl] = hv;
      doutC[grow * HH + ghl] = creg;
    }
    asm volatile("s_waitcnt vmcnt(0)" ::: "memory");
    __syncthreads();
    if (tid == 0) {
      if (!mixed) st_plain(myflag, (u32)(t + 1));
      else __hip_atomic_store(myflag, (u32)(t + 1), __ATOMIC_RELAXED, __HIP_MEMORY_SCOPE_AGENT);
    }
  }
}

// ---------------- host ----------------
extern "C" void kernel_launch(void* const* d_in, const int* in_sizes, int n_in,
                              void* d_out, int out_size, void* d_ws, size_t ws_size,
                              hipStream_t stream)
{
  const float* inputs = (const float*)d_in[0];
  const float* W_xi = (const float*)d_in[1];
  const float* W_hi = (const float*)d_in[2];
  const float* b_i  = (const float*)d_in[3];
  const float* W_xf = (const float*)d_in[4];
  const float* W_hf = (const float*)d_in[5];
  const float* b_f  = (const float*)d_in[6];
  const float* W_xo = (const float*)d_in[7];
  const float* W_ho = (const float*)d_in[8];
  const float* b_o  = (const float*)d_in[9];
  const float* W_xc = (const float*)d_in[10];
  const float* W_hc = (const float*)d_in[11];
  const float* b_c  = (const float*)d_in[12];
  float* out = (float*)d_out;
  char* ws = (char*)d_ws;

  size_t off = 0;
  auto walloc = [&](size_t sz) { size_t o = off; off = (off + sz + 255) & ~(size_t)255; return o; };
  const size_t o_inbf  = walloc((size_t)TT * BB * DD * 2);   // 64 MB
  const size_t o_WxT   = walloc((size_t)NG * DD * 2);        // 2 MB
  const size_t o_WhT   = walloc((size_t)NG * HH * 2);        // 2 MB
  const size_t o_bias  = walloc((size_t)NG * 4);
  const size_t o_Hh    = walloc((size_t)TT * BB * HH * 2);   // 64 MB
  const size_t o_ctl   = walloc(256);
  const size_t o_flags = walloc(8192);
  const size_t o_X     = walloc((size_t)TT * BB * NG * 2);   // 256 MB

  u16*   inbf  = (u16*)(ws + o_inbf);
  u16*   WxT   = (u16*)(ws + o_WxT);
  u16*   WhT   = (u16*)(ws + o_WhT);
  float* biasp = (float*)(ws + o_bias);
  u16*   Xbuf  = (u16*)(ws + o_X);
  u16*   Hh    = (u16*)(ws + o_Hh);

  k_cast<<<dim3((TT * BB * DD) / 1024), dim3(256), 0, stream>>>(inputs, inbf, (long)TT * BB * DD);
  k_pack<<<dim3(DD), dim3(256), 0, stream>>>(W_xi, W_hi, b_i, W_xf, W_hf, b_f,
                                             W_xo, W_ho, b_o, W_xc, W_hc, b_c,
                                             WxT, WhT, biasp);
  k_gemm_x<<<dim3(NG / 128, (TT * BB) / 128), dim3(256), 0, stream>>>(
      inbf, WxT, biasp, Xbuf);

  float* doutH = out + (size_t)TT * BB * HH;
  float* doutC = doutH + (size_t)BB * HH;

  hipMemsetAsync(ws + o_ctl, 0, 256, stream);
  hipMemsetAsync(ws + o_flags, 0, 8192, stream);

  k_lstm<<<dim3(NLW), dim3(512), 0, stream>>>(
      Xbuf, WhT, Hh, out, doutH, doutC,
      (u32*)(ws + o_ctl), (u32*)(ws + o_flags));
}